// Round 10
// baseline (296.329 us; speedup 1.0000x reference)
//
#include <hip/hip_runtime.h>

typedef float f32x4 __attribute__((ext_vector_type(4)));
typedef __bf16 bf16x4 __attribute__((ext_vector_type(4)));
typedef __bf16 bf16x8 __attribute__((ext_vector_type(8)));
typedef short s16x4 __attribute__((ext_vector_type(4)));

#define DEVI static __device__ __forceinline__

#define LOG2E 1.4426950408889634f
#define QSCALE (0.17677669529663687f * 1.4426950408889634f)

DEVI f32x4 mfma_k32(bf16x8 a, bf16x8 b, f32x4 c) {
    return __builtin_amdgcn_mfma_f32_16x16x32_bf16(a, b, c, 0, 0, 0);
}

union B4 { bf16x4 h; s16x4 s; };
// 16x16x16 bf16 MFMA: A/B frag k-index = (lane>>4)*4+j == C/D reg layout -> lane-local refragment
DEVI f32x4 mfma_k16(bf16x4 a, bf16x4 b, f32x4 c) {
    B4 ua, ub; ua.h = a; ub.h = b;
    return __builtin_amdgcn_mfma_f32_16x16x16bf16_1k(ua.s, ub.s, c, 0, 0, 0);
}

// TRANS ops via builtins (NOT inline asm): v_exp/v_rcp results need a HW wait
// state; the compiler inserts it for intrinsics but cannot see inside asm().
DEVI float exp2_hw(float x) { return __builtin_amdgcn_exp2f(x); }
DEVI float rcp_hw(float x)  { return __builtin_amdgcn_rcpf(x); }

union F8 { bf16x8 v; bf16x4 h[2]; };

DEVI bf16x8 ld8_lds(const __bf16* p) {   // 16B fragment from LDS (two b64 reads)
    F8 f;
    f.h[0] = *(const bf16x4*)p;
    f.h[1] = *(const bf16x4*)(p + 4);
    return f.v;
}
DEVI bf16x8 ld8_gb(const __bf16* p) { return *(const bf16x8*)p; }  // 16B global
DEVI bf16x8 ldf8(const float* p) {       // 8 fp32 -> bf16x8
    f32x4 a = *(const f32x4*)p;
    f32x4 b = *(const f32x4*)(p + 4);
    F8 f;
#pragma unroll
    for (int j = 0; j < 4; ++j) {
        f.h[0][j] = (__bf16)a[j];
        f.h[1][j] = (__bf16)b[j];
    }
    return f.v;
}
DEVI bf16x4 pk4(f32x4 v) {
    bf16x4 r;
#pragma unroll
    for (int j = 0; j < 4; ++j) r[j] = (__bf16)v[j];
    return r;
}

// ---- pre-kernel (merged):
// blocks 0..127: weights fp32 -> bf16, re-tiled into MFMA-fragment order.
//   elem = W[t*16 + (l&15)][kc*32 + (l>>4)*8 + j] -> flat ((t*8+kc)*64+l)*8+j
//   tiles 0..47 = qkv rows 0..767 (Q tiles 0..15 pre-scaled by QSCALE),
//   tiles 48..63 = proj rows 0..255.
// blocks 128..639: bias+mask table bm[cls][h][qt][kt][lane][r] f32 (512 KB),
//   fragment-ordered, pre-scaled by LOG2E (softmax runs in exp2 domain).
__global__ __launch_bounds__(256) void k_pre(const float* __restrict__ wqkv,
                                             const float* __restrict__ wp,
                                             const float* __restrict__ btab,
                                             __bf16* __restrict__ wout,
                                             float* __restrict__ bmout) {
    int bid = blockIdx.x;
    if (bid < 128) {
        int i = bid * 256 + threadIdx.x;             // one per (t,kc,l)
        int t = i >> 9, kc = (i >> 6) & 7, l = i & 63;
        int row = t * 16 + (l & 15);
        int col = kc * 32 + (l >> 4) * 8;
        const float* src = (t < 48) ? (wqkv + row * 256 + col)
                                    : (wp + (row - 768) * 256 + col);
        float s = (t < 16) ? QSCALE : 1.0f;          // fold q-scale*log2e into Wq
        f32x4 a = *(const f32x4*)src;
        f32x4 b = *(const f32x4*)(src + 4);
        F8 f;
#pragma unroll
        for (int j = 0; j < 4; ++j) {
            f.h[0][j] = (__bf16)(a[j] * s);
            f.h[1][j] = (__bf16)(b[j] * s);
        }
        *(bf16x8*)(wout + (size_t)i * 8) = f.v;
    } else {
        int i = (bid - 128) * 256 + threadIdx.x;     // 0..131071
        int r = i & 3, lane = (i >> 2) & 63;
        int kt = (i >> 8) & 3, qt = (i >> 10) & 3, h = (i >> 12) & 7, cls = i >> 15;
        int li = lane & 15, g = lane >> 4;
        int q = 16 * qt + li;
        int key = 16 * kt + 4 * g + r;
        float v;
        if (key >= 49) {
            v = -30000.f;                            // pad keys: masked for all rows
        } else if (q >= 49) {
            v = 0.f;                                 // pad q rows: don't-care
        } else {
            int qi = q / 7, qj = q - 7 * qi;
            int ki = key / 7, kj = key - 7 * ki;
            float bias = btab[((qi - ki + 6) * 13 + (qj - kj + 6)) * 8 + h];
            int ch = cls >> 1, cw = cls & 1;
            int gq = (ch ? (qi < 4 ? 1 : 2) : 0) * 3 + (cw ? (qj < 4 ? 1 : 2) : 0);
            int gk = (ch ? (ki < 4 ? 1 : 2) : 0) * 3 + (cw ? (kj < 4 ? 1 : 2) : 0);
            v = bias + ((gq != gk) ? -100.f : 0.f);
        }
        bmout[i] = v * LOG2E;                        // exp2-domain softmax
    }
}

// ---------------------------------------------------------------------------
// Fused shifted-window attention. 1 block = 1 window, 8 waves = 8 heads.
// Register budget engineered for 6 waves/EU (3 blocks/CU): every phase's
// live set <= ~82 VGPRs (per-ct V split, per-tt x loads, streaming softmax).
// LDS 51.7 KB -> 3 blocks/CU fit. Phases Q -> K -> V -> fused -> proj.
// ---------------------------------------------------------------------------
__global__ __launch_bounds__(512)
__attribute__((amdgpu_waves_per_eu(6))) void k_swin(
    const float* __restrict__ x,      // [32,56,56,256] fp32
    const __bf16* __restrict__ wb,    // tiled weights (ws): 64 tiles x 4096
    const float* __restrict__ bqkv,   // [768]
    const float* __restrict__ bm,     // [4][8][4][4][64][4] f32 bias+mask (log2e)
    const float* __restrict__ pbias,  // [256]
    float* __restrict__ out)          // [32,56,56,256] fp32
{
    __shared__ __align__(16) unsigned char smem[51216];
    __bf16* xw = (__bf16*)(smem);                 // [49][260] staged window (bf16)
    __bf16* cb = (__bf16*)(smem + 25480);         // [49][260] ctx (attn output)
    unsigned* obase = (unsigned*)(smem + 50960);  // [49] output base offsets

    const int tid = threadIdx.x;
    const int wid = tid >> 6, lane = tid & 63;
    const int li = lane & 15, g = lane >> 4;
    const int blk = blockIdx.x;
    const int b = blk >> 6, wi = blk & 63;
    const int wh = wi >> 3, ww = wi & 7;
    const int h = wid;                            // wave == head
    const int cls = ((wh == 7) ? 2 : 0) + ((ww == 7) ? 1 : 0);

    // ---- stage shifted window (fp32 -> bf16) ----
    for (int c = tid; c < 49 * 32; c += 512) {
        int tok = c >> 5, part = c & 31;
        int i = tok / 7, j = tok - 7 * i;
        int r = wh * 7 + i + 3;  if (r >= 56) r -= 56;
        int cc = ww * 7 + j + 3; if (cc >= 56) cc -= 56;
        F8 f; f.v = ldf8(x + (((size_t)(b * 56 + r) * 56 + cc) << 8) + (part << 3));
        __bf16* dst = xw + tok * 260 + (part << 3);
        *(bf16x4*)dst = f.h[0];
        *(bf16x4*)(dst + 4) = f.h[1];
    }
    if (tid < 49) {                                  // output base addresses
        int i = tid / 7, j = tid - 7 * i;
        int r = wh * 7 + i + 3;  if (r >= 56) r -= 56;
        int cc = ww * 7 + j + 3; if (cc >= 56) cc -= 56;
        obase[tid] = ((unsigned)((b * 56 + r) * 56 + cc)) << 8;
    }
    __syncthreads();   // barrier #1 (xw/obase ready; read-only afterwards)

    const f32x4 zf = {0.f, 0.f, 0.f, 0.f};
    const __bf16* wqb = wb + (size_t)(2 * h) * 4096 + lane * 8;  // q tiles 2h,2h+1
    const __bf16* wkb = wqb + 16 * 4096;                          // k tiles +16
    const __bf16* wvb = wqb + 32 * 4096;                          // v tiles +32

    bf16x4 qf[4][2], kf[4][2];   // frags: row=li=tok, k=4g+j=ch(16ct+4g+j)

    // ---- Phase 1a: Q GEMM (acc[ct][tt]: ch=16ct+4g+r, tok=16tt+li) ----
    {
        f32x4 acc[2][4];
#pragma unroll
        for (int ct = 0; ct < 2; ++ct) {
            f32x4 bq = *(const f32x4*)(bqkv + h * 32 + 16 * ct + 4 * g) * QSCALE;
#pragma unroll
            for (int tt = 0; tt < 4; ++tt) acc[ct][tt] = bq;
        }
#pragma unroll
        for (int kc = 0; kc < 8; ++kc) {
            bf16x8 aq0 = ld8_gb(wqb + kc * 512);
            bf16x8 aq1 = ld8_gb(wqb + 4096 + kc * 512);
#pragma unroll
            for (int tt = 0; tt < 4; ++tt) {
                int row = 16 * tt + li; if (row > 48) row = 48;   // clamp pad rows
                bf16x8 xf = ld8_lds(xw + row * 260 + kc * 32 + g * 8);
                acc[0][tt] = mfma_k32(aq0, xf, acc[0][tt]);
                acc[1][tt] = mfma_k32(aq1, xf, acc[1][tt]);
            }
        }
#pragma unroll
        for (int ct = 0; ct < 2; ++ct)
#pragma unroll
            for (int tt = 0; tt < 4; ++tt)
#pragma unroll
                for (int r = 0; r < 4; ++r)
                    qf[tt][ct][r] = (__bf16)acc[ct][tt][r];
    }
    __builtin_amdgcn_sched_barrier(0);   // acc reused: Q dead before K allocates

    // ---- Phase 1b: K GEMM (same accumulator block) ----
    {
        f32x4 acc[2][4];
#pragma unroll
        for (int ct = 0; ct < 2; ++ct) {
            f32x4 bk = *(const f32x4*)(bqkv + 256 + h * 32 + 16 * ct + 4 * g);
#pragma unroll
            for (int tt = 0; tt < 4; ++tt) acc[ct][tt] = bk;
        }
#pragma unroll
        for (int kc = 0; kc < 8; ++kc) {
            bf16x8 ak0 = ld8_gb(wkb + kc * 512);
            bf16x8 ak1 = ld8_gb(wkb + 4096 + kc * 512);
#pragma unroll
            for (int tt = 0; tt < 4; ++tt) {
                int row = 16 * tt + li; if (row > 48) row = 48;
                bf16x8 xf = ld8_lds(xw + row * 260 + kc * 32 + g * 8);
                acc[0][tt] = mfma_k32(ak0, xf, acc[0][tt]);
                acc[1][tt] = mfma_k32(ak1, xf, acc[1][tt]);
            }
        }
#pragma unroll
        for (int ct = 0; ct < 2; ++ct)
#pragma unroll
            for (int tt = 0; tt < 4; ++tt)
#pragma unroll
                for (int r = 0; r < 4; ++r)
                    kf[tt][ct][r] = (__bf16)acc[ct][tt][r];
    }
    __builtin_amdgcn_sched_barrier(0);   // K acc dead before V allocates

    // ---- Phase 2: V GEMM per-ct (va[4] only: tok=16tt+4g+r, ch=16ct+li) ----
    bf16x4 vf[2][4];   // V^T frags [dt][kt]: row=li=d, k=4g+j=key
#pragma unroll
    for (int ct = 0; ct < 2; ++ct) {
        float bv = bqkv[512 + h * 32 + 16 * ct + li];
        f32x4 va[4];
#pragma unroll
        for (int tt = 0; tt < 4; ++tt) va[tt] = (f32x4){bv, bv, bv, bv};
#pragma unroll
        for (int kc = 0; kc < 8; ++kc) {
            bf16x8 bvw = ld8_gb(wvb + ct * 4096 + kc * 512);
#pragma unroll
            for (int tt = 0; tt < 4; ++tt) {
                int row = 16 * tt + li; if (row > 48) row = 48;
                bf16x8 xf = ld8_lds(xw + row * 260 + kc * 32 + g * 8);
                va[tt] = mfma_k32(xf, bvw, va[tt]);
            }
        }
#pragma unroll
        for (int tt = 0; tt < 4; ++tt)
#pragma unroll
            for (int r = 0; r < 4; ++r)
                vf[ct][tt][r] = (__bf16)va[tt][r];
    }
    __builtin_amdgcn_sched_barrier(0);   // va dead before fused loop

    // ---- Phase 3: fused per-qt {streaming S+exp2, PV, vector ctx store} ----
    const float* bmq = bm + cls * 32768 + h * 4096 + lane * 4;
#pragma unroll
    for (int qt = 0; qt < 4; ++qt) {
        float sum = 0.f;
        bf16x4 pp[4];  // unnormalized P frags: row=li=q, k=4g+j=key
#pragma unroll
        for (int kt = 0; kt < 4; ++kt) {
            f32x4 sv = *(const f32x4*)(bmq + qt * 1024 + kt * 256);  // bias+mask
            sv = mfma_k16(kf[kt][0], qf[qt][0], sv);
            sv = mfma_k16(kf[kt][1], qf[qt][1], sv);
#pragma unroll
            for (int r = 0; r < 4; ++r) {
                float e = exp2_hw(sv[r]);   // no max-sub: |sv|<~25, masked -> 0
                sum += e;
                pp[kt][r] = (__bf16)e;
            }
        }
        sum += __shfl_xor(sum, 16);
        sum += __shfl_xor(sum, 32);
        float inv = rcp_hw(sum);
        // PV swapped: A=vf -> d on 4g+r, B=pp -> q on li; inv is lane-local (q=li)
        const int q = 16 * qt + li;
#pragma unroll
        for (int dt = 0; dt < 2; ++dt) {
            f32x4 acc = zf;
#pragma unroll
            for (int kt = 0; kt < 4; ++kt)
                acc = mfma_k16(vf[dt][kt], pp[kt], acc);
            acc *= inv;
            bf16x4 o4 = pk4(acc);
            if (q < 49)
                *(bf16x4*)(cb + q * 260 + 32 * h + 16 * dt + 4 * g) = o4;
        }
    }
    __syncthreads();   // barrier #2 (ctx complete)

    // ---- proj: 8 waves, wave = (pm: 32 rows, pn: 64 cols) ----
    // swapped: A=wp rows -> o on 4g+r, B=cb rows -> tok on li
    const int pm = wid >> 2, pn = wid & 3;
    const __bf16* wpb = wb + (size_t)(48 + 4 * pn) * 4096 + lane * 8;

    f32x4 pacc[2][4];
#pragma unroll
    for (int nt = 0; nt < 4; ++nt) {
        f32x4 pb = *(const f32x4*)(pbias + 64 * pn + 16 * nt + 4 * g);
        pacc[0][nt] = pb;
        pacc[1][nt] = pb;
    }

#pragma unroll
    for (int kc = 0; kc < 8; ++kc) {
        bf16x8 a[2];
#pragma unroll
        for (int mt = 0; mt < 2; ++mt) {
            int row = 32 * pm + 16 * mt + li; if (row > 48) row = 48;
            a[mt] = ld8_lds(cb + row * 260 + kc * 32 + g * 8);
        }
#pragma unroll
        for (int nt = 0; nt < 4; ++nt) {
            bf16x8 bb = ld8_gb(wpb + nt * 4096 + kc * 512);
#pragma unroll
            for (int mt = 0; mt < 2; ++mt)
                pacc[mt][nt] = mfma_k32(bb, a[mt], pacc[mt][nt]);
        }
    }

    // ---- epilogue: vector fp32 scatter via obase LUT (bias pre-initialized) ----
#pragma unroll
    for (int mt = 0; mt < 2; ++mt) {
        int tok = 32 * pm + 16 * mt + li;
        if (tok < 49) {
            float* op = out + obase[tok] + 64 * pn + 4 * g;
#pragma unroll
            for (int nt = 0; nt < 4; ++nt)
                *(f32x4*)(op + 16 * nt) = pacc[mt][nt];
        }
    }
}

extern "C" void kernel_launch(void* const* d_in, const int* in_sizes, int n_in,
                              void* d_out, int out_size, void* d_ws, size_t ws_size,
                              hipStream_t stream) {
    const float* x    = (const float*)d_in[0];
    const float* wqkv = (const float*)d_in[1];
    const float* bqkv = (const float*)d_in[2];
    const float* wp   = (const float*)d_in[3];
    const float* pb   = (const float*)d_in[4];
    const float* btab = (const float*)d_in[5];
    float* out = (float*)d_out;

    __bf16* wbuf = (__bf16*)d_ws;                       // 512 KB weights (bf16)
    float* bm = (float*)((char*)d_ws + 524288);         // 512 KB bias+mask table
    k_pre<<<640, 256, 0, stream>>>(wqkv, wp, btab, wbuf, bm);
    k_swin<<<2048, 512, 0, stream>>>(x, wbuf, bqkv, bm, pb, out);
}